// Round 2
// baseline (14265.721 us; speedup 1.0000x reference)
//
#include <hip/hip_runtime.h>

typedef __attribute__((ext_vector_type(8))) short short8;
typedef __attribute__((ext_vector_type(4))) float f32x4;
typedef __attribute__((ext_vector_type(4))) int int4v;
typedef __attribute__((ext_vector_type(4))) unsigned short u16x4;
typedef unsigned short u16;

#define T_LEN 256
#define BATCH 64
#define HID   1024
#define GDIM  4128
#define K2    2048
#define NWG   172

__device__ __forceinline__ u16 f2bf(float f){
  unsigned u = __builtin_bit_cast(unsigned, f);
  return (u16)((u + 0x7fffu + ((u >> 16) & 1u)) >> 16);
}

// ---- prologue kernels -------------------------------------------------------

__global__ __launch_bounds__(1024) void repackW(const float* __restrict__ Wih,
                                                const float* __restrict__ Whh,
                                                u16* __restrict__ Wt)
{
  __shared__ float tile[32][33];
  int k = blockIdx.x * 32 + threadIdx.y;
  int c = blockIdx.y * 32 + threadIdx.x;
  float v = (k < 1024) ? Wih[(size_t)k * GDIM + c]
                       : Whh[(size_t)(k - 1024) * GDIM + c];
  tile[threadIdx.y][threadIdx.x] = v;
  __syncthreads();
  int c2 = blockIdx.y * 32 + threadIdx.y;
  int k2 = blockIdx.x * 32 + threadIdx.x;
  Wt[(size_t)c2 * K2 + k2] = f2bf(tile[threadIdx.x][threadIdx.y]);
}

__global__ __launch_bounds__(256) void gatherX(const int* __restrict__ tokens,
                                               const float* __restrict__ emb,
                                               u16* __restrict__ x,
                                               float* __restrict__ maskout)
{
  int idx = blockIdx.x;
  int tok = tokens[idx];
  const f32x4* src = (const f32x4*)&emb[(size_t)tok * HID];
  f32x4 v = src[threadIdx.x];
  u16x4 o;
  #pragma unroll
  for (int j = 0; j < 4; ++j) o[j] = f2bf(v[j]);
  *(u16x4*)&x[(size_t)idx * HID + threadIdx.x * 4] = o;
  if (threadIdx.x == 0) maskout[idx] = (tok != 0) ? 1.0f : 0.0f;
}

__global__ __launch_bounds__(256) void biasK(const float* __restrict__ bih0, const float* __restrict__ bhh0,
                                             const float* __restrict__ bih1, const float* __restrict__ bhh1,
                                             float* __restrict__ bias0, float* __restrict__ bias1)
{
  int i = blockIdx.x * 256 + threadIdx.x;
  if (i < GDIM){ bias0[i] = bih0[i] + bhh0[i]; bias1[i] = bih1[i] + bhh1[i]; }
}

__global__ __launch_bounds__(256) void zeroK(int4v* __restrict__ p)
{
  int4v z = {0,0,0,0};
  p[blockIdx.x * 256 + threadIdx.x] = z;
}

// ---- grid-wide barrier (all 172 WGs co-resident: 99KB LDS -> 1 WG/CU) ------
__device__ __forceinline__ void gbar(unsigned* cnt, unsigned target){
  __syncthreads();
  if (threadIdx.x == 0){
    __hip_atomic_fetch_add(cnt, 1u, __ATOMIC_ACQ_REL, __HIP_MEMORY_SCOPE_AGENT);
    while (__hip_atomic_load(cnt, __ATOMIC_ACQUIRE, __HIP_MEMORY_SCOPE_AGENT) < target)
      __builtin_amdgcn_s_sleep(2);
  }
  __syncthreads();
}

// ---- persistent recurrent kernel -------------------------------------------
// grid 172 x 768. Phase A: WGs 0..85 layer0 (t=s), 86..171 layer1 (t=s-1),
// 48 cols each, MFMA 16x16x32 bf16 K=2048. Phase B: WGs 0..127 -> (L=wg>>6,
// b=wg&63) gating with 256 threads.
__global__ __launch_bounds__(768) void persist(
    const u16* __restrict__ Wt0, const u16* __restrict__ Wt1,
    const float* __restrict__ bias0, const float* __restrict__ bias1,
    const u16* __restrict__ x, u16* __restrict__ h1,
    u16* __restrict__ h2pp, const u16* __restrict__ zerob,
    float* __restrict__ gates0, float* __restrict__ gates1,
    float* __restrict__ c0, float* __restrict__ c1,
    float* __restrict__ out, unsigned* __restrict__ barCnt)
{
  __shared__ __align__(16) u16 Bs[48][1032];
  __shared__ float sg[32];

  int wg = blockIdx.x;
  int tid = threadIdx.x;

  // phase A constants
  int L = (wg >= 86) ? 1 : 0;
  int wl = wg - L * 86;
  int colbase = wl * 48;
  const u16* Wt = (L ? Wt1 : Wt0) + (size_t)colbase * K2;
  float* gatesA = L ? gates1 : gates0;
  int wave = tid >> 6, lane = tid & 63;
  int mtile = wave & 3, ntile = wave >> 2;     // 4 x 3 waves
  int lo = lane & 15, hi = lane >> 4;
  int brow = mtile * 16 + lo;
  int bcol = ntile * 16 + lo;
  int colg = colbase + ntile * 16 + lo;
  float bv = (L ? bias1 : bias0)[colg];

  // phase B constants
  int Lb = (wg >> 6) & 1, bb = wg & 63;
  bool activeB = (wg < 128);

  unsigned bidx = 0;
  for (int s = 0; s <= T_LEN; ++s){
    // ---------------- phase A: matmul -> gates ----------------
    int t = L ? (s - 1) : s;
    if (t >= 0 && t < T_LEN){
      const u16* p1 = L ? (h1 + (size_t)t * (BATCH * HID))
                        : (x  + (size_t)t * (BATCH * HID));
      const u16* p2;
      if (L) p2 = (t == 0) ? zerob : (h2pp + (size_t)((t - 1) & 1) * (BATCH * HID));
      else   p2 = (t == 0) ? zerob : (h1   + (size_t)(t - 1) * (BATCH * HID));
      const u16* pa1 = p1 + (size_t)brow * HID;
      const u16* pa2 = p2 + (size_t)brow * HID;
      f32x4 acc = {0.f, 0.f, 0.f, 0.f};
      for (int ph = 0; ph < 2; ++ph){
        __syncthreads();
        for (int i = tid; i < 48 * 128; i += 768){
          int row = i >> 7, off = (i & 127) << 3;
          *(int4v*)&Bs[row][off] =
              *(const int4v*)&Wt[(size_t)row * K2 + ph * 1024 + off];
        }
        __syncthreads();
        const u16* pa = ph ? pa2 : pa1;
        #pragma unroll 4
        for (int ks = 0; ks < 32; ++ks){
          int k0 = ks * 32 + hi * 8;
          short8 a = *(const short8*)(pa + k0);
          short8 b = *(const short8*)&Bs[bcol][k0];
          acc = __builtin_amdgcn_mfma_f32_16x16x32_bf16(a, b, acc, 0, 0, 0);
        }
      }
      #pragma unroll
      for (int j = 0; j < 4; ++j){
        int br = mtile * 16 + hi * 4 + j;      // C/D: col=lane&15, row=(lane>>4)*4+j
        gatesA[(size_t)br * GDIM + colg] = acc[j] + bv;
      }
    }
    ++bidx; gbar(barCnt, (unsigned)NWG * bidx);

    // ---------------- phase B: gating -> h, c, out ----------------
    {
      int tb = Lb ? (s - 1) : s;
      bool valid = activeB && (tb >= 0) && (tb < T_LEN);
      const float* g = nullptr;
      if (valid){
        g = (Lb ? gates1 : gates0) + (size_t)bb * GDIM;
        if (tid < 32) sg[tid] = g[tid];
      }
      __syncthreads();
      if (valid && tid < 256){
        int e = tid * 4;
        int n = e >> 6;
        int k = e & 63;
        float m1 = -1e30f, m2 = -1e30f;
        #pragma unroll
        for (int i = 0; i < 16; ++i){ m1 = fmaxf(m1, sg[i]); m2 = fmaxf(m2, sg[16 + i]); }
        float s1 = 0.f, s2 = 0.f, cu1 = 0.f, cu2 = 0.f;
        #pragma unroll
        for (int i = 0; i < 16; ++i){
          float e1 = __expf(sg[i] - m1), e2 = __expf(sg[16 + i] - m2);
          s1 += e1; s2 += e2;
          if (i <= n){ cu1 += e1; cu2 += e2; }
        }
        float cin = 1.f - cu1 / s1;
        float cf  = cu2 / s2;
        float ov  = cf * cin;
        const float* gr = g + 32 + n * 64 + k;
        f32x4 og4 = *(const f32x4*)(gr);
        f32x4 ce4 = *(const f32x4*)(gr + 1024);
        f32x4 in4 = *(const f32x4*)(gr + 2048);
        f32x4 fg4 = *(const f32x4*)(gr + 3072);
        float* cbuf = (Lb ? c1 : c0) + (size_t)bb * HID + e;
        f32x4 cx;
        if (tb == 0) { cx = f32x4{0.f,0.f,0.f,0.f}; } else { cx = *(const f32x4*)cbuf; }
        f32x4 hy;
        #pragma unroll
        for (int j = 0; j < 4; ++j){
          float ogv = 1.f / (1.f + __expf(-og4[j]));
          float inv = 1.f / (1.f + __expf(-in4[j]));
          float fgv = 1.f / (1.f + __expf(-fg4[j]));
          float cev = tanhf(ce4[j]);
          float fga = fgv * ov + (cf - ov);
          float iga = inv * ov + (cin - ov);
          float cy  = fga * cx[j] + iga * cev;
          cx[j] = cy;
          hy[j] = ogv * tanhf(cy);
        }
        *(f32x4*)cbuf = cx;
        if (Lb == 0){
          u16x4 hb;
          #pragma unroll
          for (int j = 0; j < 4; ++j) hb[j] = f2bf(hy[j]);
          *(u16x4*)&h1[(size_t)tb * (BATCH * HID) + bb * HID + e] = hb;
        } else {
          *(f32x4*)&out[((size_t)tb * BATCH + bb) * HID + e] = hy;
          u16x4 hb;
          #pragma unroll
          for (int j = 0; j < 4; ++j) hb[j] = f2bf(hy[j]);
          *(u16x4*)&h2pp[(size_t)(tb & 1) * (BATCH * HID) + bb * HID + e] = hb;
        }
      }
    }
    ++bidx; gbar(barCnt, (unsigned)NWG * bidx);
  }
}

// ---- launch -----------------------------------------------------------------

extern "C" void kernel_launch(void* const* d_in, const int* in_sizes, int n_in,
                              void* d_out, int out_size, void* d_ws, size_t ws_size,
                              hipStream_t stream)
{
  (void)in_sizes; (void)n_in; (void)out_size; (void)ws_size;
  const int*   tokens = (const int*)d_in[0];
  const float* emb    = (const float*)d_in[1];
  const float* Wih0   = (const float*)d_in[2];
  const float* bih0   = (const float*)d_in[3];
  const float* Whh0   = (const float*)d_in[4];
  const float* bhh0   = (const float*)d_in[5];
  const float* Wih1   = (const float*)d_in[6];
  const float* bih1   = (const float*)d_in[7];
  const float* Whh1   = (const float*)d_in[8];
  const float* bhh1   = (const float*)d_in[9];
  float* out = (float*)d_out;

  char* ws = (char*)d_ws;
  u16*   Wt0    = (u16*)(ws);                    // 16,908,288
  u16*   Wt1    = (u16*)(ws + 16908288);         // 16,908,288
  u16*   x      = (u16*)(ws + 33816576);         // 33,554,432
  u16*   h1     = (u16*)(ws + 67371008);         // 33,554,432
  float* bias0  = (float*)(ws + 100925440);      // 16,512
  float* bias1  = (float*)(ws + 100941952);      // 16,512
  float* gates0 = (float*)(ws + 100958464);      // 1,056,768
  float* gates1 = (float*)(ws + 102015232);      // 1,056,768
  float* c0     = (float*)(ws + 103072000);      // 262,144
  float* c1     = (float*)(ws + 103334144);      // 262,144
  u16*   zerob  = (u16*)(ws + 103596288);        // 131,072 (zeroed)
  u16*   h2pp   = (u16*)(ws + 103727360);        // 262,144 (zeroed, adjacent)
  unsigned* barCnt = (unsigned*)(ws + 103989504);// 4
  // total ~104 MB

  repackW<<<dim3(64,129), dim3(32,32), 0, stream>>>(Wih0, Whh0, Wt0);
  repackW<<<dim3(64,129), dim3(32,32), 0, stream>>>(Wih1, Whh1, Wt1);
  gatherX<<<16384, 256, 0, stream>>>(tokens, emb, x, out + 16777216);
  biasK<<<17, 256, 0, stream>>>(bih0, bhh0, bih1, bhh1, bias0, bias1);
  zeroK<<<96, 256, 0, stream>>>((int4v*)zerob);
  hipMemsetAsync(barCnt, 0, 4, stream);

  persist<<<NWG, 768, 0, stream>>>(Wt0, Wt1, bias0, bias1, x, h1, h2pp, zerob,
                                   gates0, gates1, c0, c1, out, barCnt);
}

// Round 3
// 10058.792 us; speedup vs baseline: 1.4182x; 1.4182x over previous
//
#include <hip/hip_runtime.h>

typedef __attribute__((ext_vector_type(8))) short short8;
typedef __attribute__((ext_vector_type(4))) float f32x4;
typedef __attribute__((ext_vector_type(4))) int int4v;
typedef __attribute__((ext_vector_type(4))) unsigned short u16x4;
typedef unsigned short u16;

#define T_LEN 256
#define BATCH 64
#define HID   1024
#define GDIM  4128
#define K2    2048
#define NWG   172

__device__ __forceinline__ u16 f2bf(float f){
  unsigned u = __builtin_bit_cast(unsigned, f);
  return (u16)((u + 0x7fffu + ((u >> 16) & 1u)) >> 16);
}

// ---- prologue kernels -------------------------------------------------------

__global__ __launch_bounds__(1024) void repackW(const float* __restrict__ Wih,
                                                const float* __restrict__ Whh,
                                                u16* __restrict__ Wt)
{
  __shared__ float tile[32][33];
  int k = blockIdx.x * 32 + threadIdx.y;
  int c = blockIdx.y * 32 + threadIdx.x;
  float v = (k < 1024) ? Wih[(size_t)k * GDIM + c]
                       : Whh[(size_t)(k - 1024) * GDIM + c];
  tile[threadIdx.y][threadIdx.x] = v;
  __syncthreads();
  int c2 = blockIdx.y * 32 + threadIdx.y;
  int k2 = blockIdx.x * 32 + threadIdx.x;
  Wt[(size_t)c2 * K2 + k2] = f2bf(tile[threadIdx.x][threadIdx.y]);
}

__global__ __launch_bounds__(256) void gatherX(const int* __restrict__ tokens,
                                               const float* __restrict__ emb,
                                               u16* __restrict__ x,
                                               float* __restrict__ maskout)
{
  int idx = blockIdx.x;
  int tok = tokens[idx];
  const f32x4* src = (const f32x4*)&emb[(size_t)tok * HID];
  f32x4 v = src[threadIdx.x];
  u16x4 o;
  #pragma unroll
  for (int j = 0; j < 4; ++j) o[j] = f2bf(v[j]);
  *(u16x4*)&x[(size_t)idx * HID + threadIdx.x * 4] = o;
  if (threadIdx.x == 0) maskout[idx] = (tok != 0) ? 1.0f : 0.0f;
}

__global__ __launch_bounds__(256) void biasK(const float* __restrict__ bih0, const float* __restrict__ bhh0,
                                             const float* __restrict__ bih1, const float* __restrict__ bhh1,
                                             float* __restrict__ bias0, float* __restrict__ bias1)
{
  int i = blockIdx.x * 256 + threadIdx.x;
  if (i < GDIM){ bias0[i] = bih0[i] + bhh0[i]; bias1[i] = bih1[i] + bhh1[i]; }
}

__global__ __launch_bounds__(256) void zeroK(int4v* __restrict__ p)
{
  int4v z = {0,0,0,0};
  p[blockIdx.x * 256 + threadIdx.x] = z;
}

// ---- grid-wide barrier: RELAXED atomics only (no wbl2/inv cache storms) -----
// Producer completion: __syncthreads() drains vmcnt(0) on every wave; data
// handoff goes through volatile (write-through) stores, so once vmcnt==0 the
// data is at the coherence point. Spin load is relaxed (sc-bypass, no inv).
__device__ __forceinline__ void gbar(unsigned* cnt, unsigned target){
  asm volatile("s_waitcnt vmcnt(0)" ::: "memory");
  __syncthreads();
  if (threadIdx.x == 0){
    __hip_atomic_fetch_add(cnt, 1u, __ATOMIC_RELAXED, __HIP_MEMORY_SCOPE_AGENT);
    while (__hip_atomic_load(cnt, __ATOMIC_RELAXED, __HIP_MEMORY_SCOPE_AGENT) < target)
      __builtin_amdgcn_s_sleep(1);
  }
  __syncthreads();
}

// ---- persistent recurrent kernel -------------------------------------------
// grid 172 x 768, 1 WG/CU (96KB LDS). Phase A: WGs 0..85 layer0 (t=s),
// 86..171 layer1 (t=s-1), 48 cols each, MFMA 16x16x32 bf16 K=2048.
// Phase B: WGs 0..127 -> (L=wg>>6, b=wg&63), c-state in registers.
// hA/hB are FULL-HISTORY buffers: volatile-written once, cached-read at the
// next super-step only (no stale-line hazard; replay-identical values).
__global__ __launch_bounds__(768) void persist(
    const u16* __restrict__ Wt0, const u16* __restrict__ Wt1,
    const float* __restrict__ bias0, const float* __restrict__ bias1,
    const u16* __restrict__ x, u16* __restrict__ hA,
    u16* __restrict__ hB, const u16* __restrict__ zerob,
    float* __restrict__ gates0, float* __restrict__ gates1,
    float* __restrict__ out, unsigned* __restrict__ barCnt)
{
  __shared__ __align__(16) u16 Bs[48][1024];  // T2 XOR swizzle, no pad
  __shared__ float sg[32];

  int wg = blockIdx.x;
  int tid = threadIdx.x;

  // phase A constants
  int L = (wg >= 86) ? 1 : 0;
  int wl = wg - L * 86;
  int colbase = wl * 48;
  const u16* Wt = (L ? Wt1 : Wt0) + (size_t)colbase * K2;
  float* gatesA = L ? gates1 : gates0;
  int wave = tid >> 6, lane = tid & 63;
  int mtile = wave & 3, ntile = wave >> 2;     // 4 x 3 waves
  int lo = lane & 15, hi = lane >> 4;
  int brow = mtile * 16 + lo;
  int bcol = ntile * 16 + lo;
  int bswz = (bcol & 7) << 3;                  // T2: u16-index XOR per row
  int colg = colbase + ntile * 16 + lo;
  float bv = (L ? bias1 : bias0)[colg];

  // phase B constants
  int Lb = (wg >> 6) & 1, bb = wg & 63;
  bool activeB = (wg < 128);
  f32x4 creg = {0.f, 0.f, 0.f, 0.f};           // c-state lives in registers

  unsigned bidx = 0;
  for (int s = 0; s <= T_LEN; ++s){
    // ---------------- phase A: matmul -> gates (volatile stores) -----------
    int t = L ? (s - 1) : s;
    if (t >= 0 && t < T_LEN){
      const u16* p1 = L ? (hA + (size_t)t * (BATCH * HID))
                        : (x  + (size_t)t * (BATCH * HID));
      const u16* p2;
      if (L) p2 = (t == 0) ? zerob : (hB + (size_t)(t - 1) * (BATCH * HID));
      else   p2 = (t == 0) ? zerob : (hA + (size_t)(t - 1) * (BATCH * HID));
      const u16* pa1 = p1 + (size_t)brow * HID;
      const u16* pa2 = p2 + (size_t)brow * HID;
      f32x4 acc = {0.f, 0.f, 0.f, 0.f};
      for (int ph = 0; ph < 2; ++ph){
        __syncthreads();
        for (int i = tid; i < 48 * 128; i += 768){
          int row = i >> 7, off = (i & 127) << 3;
          int offs = off ^ ((row & 7) << 3);   // T2 swizzle (16B-preserving)
          *(int4v*)&Bs[row][offs] =
              *(const int4v*)&Wt[(size_t)row * K2 + ph * 1024 + off];
        }
        __syncthreads();
        const u16* pa = ph ? pa2 : pa1;
        #pragma unroll 4
        for (int ks = 0; ks < 32; ++ks){
          int k0 = ks * 32 + hi * 8;
          short8 a = *(const short8*)(pa + k0);
          short8 b = *(const short8*)&Bs[bcol][k0 ^ bswz];
          acc = __builtin_amdgcn_mfma_f32_16x16x32_bf16(a, b, acc, 0, 0, 0);
        }
      }
      #pragma unroll
      for (int j = 0; j < 4; ++j){
        int br = mtile * 16 + hi * 4 + j;      // C/D: col=lane&15, row=(lane>>4)*4+j
        *(volatile float*)&gatesA[(size_t)br * GDIM + colg] = acc[j] + bv;
      }
    }
    ++bidx; gbar(barCnt, (unsigned)NWG * bidx);

    // ---------------- phase B: gating -> h (volatile), c (regs), out ------
    if (activeB){
      int tb = Lb ? (s - 1) : s;
      bool valid = (tb >= 0) && (tb < T_LEN);
      const float* g = (Lb ? gates1 : gates0) + (size_t)bb * GDIM;
      if (valid && tid < 32) sg[tid] = *(volatile const float*)(g + tid);
      __syncthreads();
      if (valid && tid < 256){
        int e = tid * 4;
        int n = e >> 6;
        int k = e & 63;
        float m1 = -1e30f, m2 = -1e30f;
        #pragma unroll
        for (int i = 0; i < 16; ++i){ m1 = fmaxf(m1, sg[i]); m2 = fmaxf(m2, sg[16 + i]); }
        float s1 = 0.f, s2 = 0.f, cu1 = 0.f, cu2 = 0.f;
        #pragma unroll
        for (int i = 0; i < 16; ++i){
          float e1 = __expf(sg[i] - m1), e2 = __expf(sg[16 + i] - m2);
          s1 += e1; s2 += e2;
          if (i <= n){ cu1 += e1; cu2 += e2; }
        }
        float cin = 1.f - cu1 / s1;
        float cf  = cu2 / s2;
        float ov  = cf * cin;
        const volatile float* gr = (const volatile float*)(g + 32 + n * 64 + k);
        f32x4 og4 = *(const volatile f32x4*)(gr);
        f32x4 ce4 = *(const volatile f32x4*)(gr + 1024);
        f32x4 in4 = *(const volatile f32x4*)(gr + 2048);
        f32x4 fg4 = *(const volatile f32x4*)(gr + 3072);
        if (tb == 0) creg = f32x4{0.f,0.f,0.f,0.f};
        f32x4 hy;
        #pragma unroll
        for (int j = 0; j < 4; ++j){
          float ogv = 1.f / (1.f + __expf(-og4[j]));
          float inv = 1.f / (1.f + __expf(-in4[j]));
          float fgv = 1.f / (1.f + __expf(-fg4[j]));
          float cev = tanhf(ce4[j]);
          float fga = fgv * ov + (cf - ov);
          float iga = inv * ov + (cin - ov);
          float cy  = fga * creg[j] + iga * cev;
          creg[j] = cy;
          hy[j] = ogv * tanhf(cy);
        }
        u16x4 hb;
        #pragma unroll
        for (int j = 0; j < 4; ++j) hb[j] = f2bf(hy[j]);
        if (Lb == 0){
          *(volatile u16x4*)&hA[(size_t)tb * (BATCH * HID) + bb * HID + e] = hb;
        } else {
          *(f32x4*)&out[((size_t)tb * BATCH + bb) * HID + e] = hy;
          *(volatile u16x4*)&hB[(size_t)tb * (BATCH * HID) + bb * HID + e] = hb;
        }
      }
    }
    ++bidx; gbar(barCnt, (unsigned)NWG * bidx);
  }
}

// ---- launch -----------------------------------------------------------------

extern "C" void kernel_launch(void* const* d_in, const int* in_sizes, int n_in,
                              void* d_out, int out_size, void* d_ws, size_t ws_size,
                              hipStream_t stream)
{
  (void)in_sizes; (void)n_in; (void)out_size; (void)ws_size;
  const int*   tokens = (const int*)d_in[0];
  const float* emb    = (const float*)d_in[1];
  const float* Wih0   = (const float*)d_in[2];
  const float* bih0   = (const float*)d_in[3];
  const float* Whh0   = (const float*)d_in[4];
  const float* bhh0   = (const float*)d_in[5];
  const float* Wih1   = (const float*)d_in[6];
  const float* bih1   = (const float*)d_in[7];
  const float* Whh1   = (const float*)d_in[8];
  const float* bhh1   = (const float*)d_in[9];
  float* out = (float*)d_out;

  char* ws = (char*)d_ws;
  u16*   Wt0    = (u16*)(ws);                     // 16,908,288
  u16*   Wt1    = (u16*)(ws + 16908288);          // 16,908,288
  u16*   x      = (u16*)(ws + 33816576);          // 33,554,432
  u16*   hA     = (u16*)(ws + 67371008);          // 33,554,432 (full history)
  u16*   hB     = (u16*)(ws + 100925440);         // 33,554,432 (full history)
  float* bias0  = (float*)(ws + 134479872);       // 16,512
  float* bias1  = (float*)(ws + 134496384);       // 16,512
  float* gates0 = (float*)(ws + 134512896);       // 1,056,768
  float* gates1 = (float*)(ws + 135569664);       // 1,056,768
  u16*   zerob  = (u16*)(ws + 136626432);         // 131,072 (zeroed)
  unsigned* barCnt = (unsigned*)(ws + 136757504); // 4
  // total ~130.5 MB

  repackW<<<dim3(64,129), dim3(32,32), 0, stream>>>(Wih0, Whh0, Wt0);
  repackW<<<dim3(64,129), dim3(32,32), 0, stream>>>(Wih1, Whh1, Wt1);
  gatherX<<<16384, 256, 0, stream>>>(tokens, emb, x, out + 16777216);
  biasK<<<17, 256, 0, stream>>>(bih0, bhh0, bih1, bhh1, bias0, bias1);
  zeroK<<<32, 256, 0, stream>>>((int4v*)zerob);
  hipMemsetAsync(barCnt, 0, 4, stream);

  persist<<<NWG, 768, 0, stream>>>(Wt0, Wt1, bias0, bias1, x, hA, hB, zerob,
                                   gates0, gates1, out, barCnt);
}

// Round 4
// 8274.017 us; speedup vs baseline: 1.7242x; 1.2157x over previous
//
#include <hip/hip_runtime.h>

typedef __attribute__((ext_vector_type(8))) short short8;
typedef __attribute__((ext_vector_type(4))) float f32x4;
typedef __attribute__((ext_vector_type(4))) int int4v;
typedef __attribute__((ext_vector_type(4))) unsigned short u16x4;
typedef unsigned short u16;

#define T_LEN 256
#define BATCH 64
#define HID   1024
#define GDIM  4128
#define BH    65536
#define NWG   194
#define R1B   65

__device__ __forceinline__ u16 f2bf(float f){
  unsigned u = __builtin_bit_cast(unsigned, f);
  return (u16)((u + 0x7fffu + ((u >> 16) & 1u)) >> 16);
}

// ---- prologue kernels -------------------------------------------------------

__global__ __launch_bounds__(1024) void repackW(const float* __restrict__ Wih,
                                                const float* __restrict__ Whh,
                                                u16* __restrict__ Wt)
{
  __shared__ float tile[32][33];
  int k = blockIdx.x * 32 + threadIdx.y;
  int c = blockIdx.y * 32 + threadIdx.x;
  float v = (k < 1024) ? Wih[(size_t)k * GDIM + c]
                       : Whh[(size_t)(k - 1024) * GDIM + c];
  tile[threadIdx.y][threadIdx.x] = v;
  __syncthreads();
  int c2 = blockIdx.y * 32 + threadIdx.y;
  int k2 = blockIdx.x * 32 + threadIdx.x;
  Wt[(size_t)c2 * 2048 + k2] = f2bf(tile[threadIdx.x][threadIdx.y]);
}

__global__ __launch_bounds__(256) void gatherX(const int* __restrict__ tokens,
                                               const float* __restrict__ emb,
                                               u16* __restrict__ x,
                                               float* __restrict__ maskout)
{
  int idx = blockIdx.x;
  int tok = tokens[idx];
  const f32x4* src = (const f32x4*)&emb[(size_t)tok * HID];
  f32x4 v = src[threadIdx.x];
  u16x4 o;
  #pragma unroll
  for (int j = 0; j < 4; ++j) o[j] = f2bf(v[j]);
  *(u16x4*)&x[(size_t)idx * HID + threadIdx.x * 4] = o;
  if (threadIdx.x == 0) maskout[idx] = (tok != 0) ? 1.0f : 0.0f;
}

__global__ __launch_bounds__(256) void biasK(const float* __restrict__ bih0, const float* __restrict__ bhh0,
                                             const float* __restrict__ bih1, const float* __restrict__ bhh1,
                                             float* __restrict__ bias0, float* __restrict__ bias1)
{
  int i = blockIdx.x * 256 + threadIdx.x;
  if (i < GDIM){ bias0[i] = bih0[i] + bhh0[i]; bias1[i] = bih1[i] + bhh1[i]; }
}

__global__ __launch_bounds__(256) void zeroK(int4v* __restrict__ p)
{
  int4v z = {0,0,0,0};
  p[blockIdx.x * 256 + threadIdx.x] = z;
}

// ---- barrier pieces: relaxed atomics, 8-way sharded counters ----------------
__device__ __forceinline__ void drain_sync(){
  asm volatile("s_waitcnt vmcnt(0)" ::: "memory");
  __syncthreads();
}
__device__ __forceinline__ void bar_add(unsigned* set, int wg){
  if (threadIdx.x == 0)
    __hip_atomic_fetch_add(&set[(wg & 7) * 32], 1u, __ATOMIC_RELAXED, __HIP_MEMORY_SCOPE_AGENT);
}
__device__ __forceinline__ void bar_spin(unsigned* set, unsigned target){
  if (threadIdx.x == 0){
    for (;;){
      unsigned sm = 0;
      #pragma unroll
      for (int i = 0; i < 8; ++i)
        sm += __hip_atomic_load(&set[i * 32], __ATOMIC_RELAXED, __HIP_MEMORY_SCOPE_AGENT);
      if (sm >= target) break;
      __builtin_amdgcn_s_sleep(1);
    }
  }
  __syncthreads();
}

// x-projection for layer 0, step tt (no sequential dependency; runs in the
// barrier window). B-frags from global (L2-resident W_ih0 slice).
__device__ __forceinline__ void xproj_f(const u16* px, const u16* w0, const u16* w1,
                                        float b0, float b1, int khi,
                                        f32x4& xn0, f32x4& xn1){
  f32x4 t0 = {b0, b0, b0, b0}, t1 = {b1, b1, b1, b1};
  #pragma unroll
  for (int blk = 0; blk < 4; ++blk){
    short8 xa[8], xb0[8], xb1[8];
    #pragma unroll
    for (int i = 0; i < 8; ++i){ int j = blk * 8 + i;
      xa[i]  = *(const short8*)(px + j * 32 + khi);
      xb0[i] = *(const short8*)(w0 + j * 32 + khi);
      xb1[i] = *(const short8*)(w1 + j * 32 + khi); }
    #pragma unroll
    for (int i = 0; i < 8; ++i){
      t0 = __builtin_amdgcn_mfma_f32_16x16x32_bf16(xa[i], xb0[i], t0, 0, 0, 0);
      t1 = __builtin_amdgcn_mfma_f32_16x16x32_bf16(xa[i], xb1[i], t1, 0, 0, 0); }
  }
  xn0 = t0; xn1 = t1;
}

// ---- persistent recurrent kernel -------------------------------------------
// 194 WGs x 512 thr, 1 WG/CU (128KB LDS, weights LDS-resident, staged once).
// R0 = wg 0..64: layer-0, 64 cols (last 32): gates0[s] = xn(regs) + h1[s-1]@W_hh0.
//   Also computes xn for s+1 (x@W_ih0+bias) inside the bar2 window.
// R1 = wg 65..193: layer-1, 32 cols: gates1 = bias1 + h1[s-1]@W_ih1 + h2[s-2]@W_hh1.
// Phase B on wg 65..192 (unit = wg-65): gating, c in registers.
__global__ __launch_bounds__(512, 2) void persist(
    const u16* __restrict__ Wt0, const u16* __restrict__ Wt1,
    const float* __restrict__ bias0, const float* __restrict__ bias1,
    const u16* __restrict__ x, u16* __restrict__ hA, u16* __restrict__ hB,
    const u16* __restrict__ zerob,
    float* __restrict__ gates0, float* __restrict__ gates1,
    float* __restrict__ out, unsigned* __restrict__ bar1, unsigned* __restrict__ bar2)
{
  __shared__ __align__(16) u16 Ws[65536];   // 128 KB persistent weight slice
  __shared__ float sg[32];

  const int wg  = blockIdx.x;
  const int tid = threadIdx.x;
  const int wave = tid >> 6, lane = tid & 63;
  const int lo = lane & 15, hi = lane >> 4;
  const int khi = hi * 8;
  const int mt = wave >> 1, nw = wave & 1;          // 4 M-tiles x 2 N-waves
  const int row = mt * 16 + lo;
  const bool isR0 = (wg < R1B);

  // ---- one-time LDS weight staging (XOR-swizzled, 16B-preserving) ----
  if (isR0){
    const int colbase = wg * 64;
    const int ncols = (colbase + 64 <= GDIM) ? 64 : (GDIM - colbase);
    for (int i = tid; i < ncols * 128; i += 512){
      int r = i >> 7, ck = (i & 127) << 3;
      *(int4v*)&Ws[r * 1024 + (ck ^ ((r & 7) << 3))] =
        *(const int4v*)&Wt0[(size_t)(colbase + r) * 2048 + 1024 + ck];
    }
  } else {
    const int colbase = (wg - R1B) * 32;
    for (int i = tid; i < 32 * 256; i += 512){
      int r = i >> 8, ck = (i & 255) << 3;
      *(int4v*)&Ws[r * 2048 + (ck ^ ((r & 7) << 3))] =
        *(const int4v*)&Wt1[(size_t)(colbase + r) * 2048 + ck];
    }
  }
  __syncthreads();

  // ---- per-role constants ----
  const int colbase0 = wg * 64;
  const int cg0 = colbase0 + nw * 32 + lo;
  const int cg1 = cg0 + 16;
  const int cA  = nw * 32 + lo;
  const int offA = cA * 1024;
  const int offB = (cA + 16) * 1024;
  const int swA  = (cA & 7) << 3;                    // same for cA+16
  const u16* wi0p = Wt0 + (size_t)(cg0 < GDIM ? cg0 : GDIM - 1) * 2048;
  const u16* wi1p = Wt0 + (size_t)(cg1 < GDIM ? cg1 : GDIM - 1) * 2048;

  const int colbase1 = (wg - R1B) * 32;
  const int cgR = colbase1 + nw * 16 + lo;
  const int cR  = nw * 16 + lo;
  const int offR = cR * 2048;
  const int swR  = (cR & 7) << 3;

  float bv00 = 0.f, bv01 = 0.f, bvR = 0.f;
  if (isR0){
    bv00 = bias0[cg0 < GDIM ? cg0 : 0];
    bv01 = bias0[cg1 < GDIM ? cg1 : 0];
  } else {
    bvR = bias1[cgR];
  }

  f32x4 xn0 = {0.f,0.f,0.f,0.f}, xn1 = {0.f,0.f,0.f,0.f};
  if (isR0)
    xproj_f(x + (size_t)0 * BH + row * HID, wi0p, wi1p, bv00, bv01, khi, xn0, xn1);

  f32x4 creg = {0.f, 0.f, 0.f, 0.f};

  for (int s = 0; s <= T_LEN; ++s){
    const unsigned tgt = (unsigned)NWG * (unsigned)(s + 1);

    if (isR0){
      // ---------------- phase A: layer-0 recurrent ----------------
      if (s < T_LEN){
        const u16* pH = (s == 0) ? (zerob + row * HID)
                                 : (hA + (size_t)(s - 1) * BH + row * HID);
        f32x4 a0 = xn0, a1 = xn1;
        short8 A0[16], A1[16];
        #pragma unroll
        for (int i = 0; i < 16; ++i) A0[i] = *(const short8*)(pH + i * 32 + khi);
        #pragma unroll
        for (int i = 0; i < 16; ++i) A1[i] = *(const short8*)(pH + 512 + i * 32 + khi);
        #pragma unroll
        for (int i = 0; i < 16; ++i){
          a0 = __builtin_amdgcn_mfma_f32_16x16x32_bf16(A0[i], *(const short8*)&Ws[offA + ((i*32 + khi) ^ swA)], a0, 0,0,0);
          a1 = __builtin_amdgcn_mfma_f32_16x16x32_bf16(A0[i], *(const short8*)&Ws[offB + ((i*32 + khi) ^ swA)], a1, 0,0,0);
        }
        #pragma unroll
        for (int i = 0; i < 16; ++i){
          a0 = __builtin_amdgcn_mfma_f32_16x16x32_bf16(A1[i], *(const short8*)&Ws[offA + (((16+i)*32 + khi) ^ swA)], a0, 0,0,0);
          a1 = __builtin_amdgcn_mfma_f32_16x16x32_bf16(A1[i], *(const short8*)&Ws[offB + (((16+i)*32 + khi) ^ swA)], a1, 0,0,0);
        }
        #pragma unroll
        for (int j = 0; j < 4; ++j){
          int br = mt * 16 + hi * 4 + j;
          if (cg0 < GDIM) *(volatile float*)&gates0[(size_t)br * GDIM + cg0] = a0[j];
          if (cg1 < GDIM) *(volatile float*)&gates0[(size_t)br * GDIM + cg1] = a1[j];
        }
      }
      drain_sync();
      bar_add(bar1, wg);
      bar_add(bar2, wg);
      if (s + 1 < T_LEN)     // xproj for next step, hidden in bar/phase-B window
        xproj_f(x + (size_t)(s + 1) * BH + row * HID, wi0p, wi1p, bv00, bv01, khi, xn0, xn1);
      bar_spin(bar2, tgt);
    } else {
      // ---------------- phase A: layer-1 ----------------
      if (s >= 1){
        const int t1 = s - 1;
        const u16* pH1 = hA + (size_t)t1 * BH + row * HID;
        const u16* pH2 = (t1 == 0) ? (zerob + row * HID)
                                   : (hB + (size_t)(t1 - 1) * BH + row * HID);
        f32x4 acc = {bvR, bvR, bvR, bvR};
        short8 A0[16], A1[16];
        #pragma unroll
        for (int i = 0; i < 16; ++i) A0[i] = *(const short8*)(pH1 + i * 32 + khi);
        #pragma unroll
        for (int i = 0; i < 16; ++i) A1[i] = *(const short8*)(pH1 + 512 + i * 32 + khi);
        #pragma unroll
        for (int i = 0; i < 16; ++i)
          acc = __builtin_amdgcn_mfma_f32_16x16x32_bf16(A0[i], *(const short8*)&Ws[offR + ((i*32 + khi) ^ swR)], acc, 0,0,0);
        #pragma unroll
        for (int i = 0; i < 16; ++i) A0[i] = *(const short8*)(pH2 + i * 32 + khi);
        #pragma unroll
        for (int i = 0; i < 16; ++i)
          acc = __builtin_amdgcn_mfma_f32_16x16x32_bf16(A1[i], *(const short8*)&Ws[offR + (((16+i)*32 + khi) ^ swR)], acc, 0,0,0);
        #pragma unroll
        for (int i = 0; i < 16; ++i) A1[i] = *(const short8*)(pH2 + 512 + i * 32 + khi);
        #pragma unroll
        for (int i = 0; i < 16; ++i)
          acc = __builtin_amdgcn_mfma_f32_16x16x32_bf16(A0[i], *(const short8*)&Ws[offR + (((32+i)*32 + khi) ^ swR)], acc, 0,0,0);
        #pragma unroll
        for (int i = 0; i < 16; ++i)
          acc = __builtin_amdgcn_mfma_f32_16x16x32_bf16(A1[i], *(const short8*)&Ws[offR + (((48+i)*32 + khi) ^ swR)], acc, 0,0,0);
        #pragma unroll
        for (int j = 0; j < 4; ++j){
          int br = mt * 16 + hi * 4 + j;
          *(volatile float*)&gates1[(size_t)br * GDIM + cgR] = acc[j];
        }
      }
      drain_sync();
      bar_add(bar1, wg);
      if (wg < 193){
        bar_spin(bar1, tgt);
        // ---------------- phase B: gating ----------------
        const int u  = wg - R1B;
        const int Lb = u >> 6, bb = u & 63;
        const int tb = Lb ? (s - 1) : s;
        const bool valid = (tb >= 0) && (tb < T_LEN);
        const float* g = (Lb ? gates1 : gates0) + (size_t)bb * GDIM;
        if (valid && tid < 32) sg[tid] = *(volatile const float*)(g + tid);
        __syncthreads();
        if (valid && tid < 256){
          int e = tid * 4;
          int n = e >> 6;
          int k = e & 63;
          float m1 = -1e30f, m2 = -1e30f;
          #pragma unroll
          for (int i = 0; i < 16; ++i){ m1 = fmaxf(m1, sg[i]); m2 = fmaxf(m2, sg[16 + i]); }
          float s1 = 0.f, s2 = 0.f, cu1 = 0.f, cu2 = 0.f;
          #pragma unroll
          for (int i = 0; i < 16; ++i){
            float e1 = __expf(sg[i] - m1), e2 = __expf(sg[16 + i] - m2);
            s1 += e1; s2 += e2;
            if (i <= n){ cu1 += e1; cu2 += e2; }
          }
          float cin = 1.f - cu1 / s1;
          float cf  = cu2 / s2;
          float ov  = cf * cin;
          const float* gr = g + 32 + n * 64 + k;
          f32x4 og4 = *(const volatile f32x4*)(gr);
          f32x4 ce4 = *(const volatile f32x4*)(gr + 1024);
          f32x4 in4 = *(const volatile f32x4*)(gr + 2048);
          f32x4 fg4 = *(const volatile f32x4*)(gr + 3072);
          if (tb == 0) creg = f32x4{0.f, 0.f, 0.f, 0.f};
          f32x4 hy;
          #pragma unroll
          for (int j = 0; j < 4; ++j){
            float ogv = 1.f / (1.f + __expf(-og4[j]));
            float inv = 1.f / (1.f + __expf(-in4[j]));
            float fgv = 1.f / (1.f + __expf(-fg4[j]));
            float cev = tanhf(ce4[j]);
            float fga = fgv * ov + (cf - ov);
            float iga = inv * ov + (cin - ov);
            float cy  = fga * creg[j] + iga * cev;
            creg[j] = cy;
            hy[j] = ogv * tanhf(cy);
          }
          u16x4 hb;
          #pragma unroll
          for (int j = 0; j < 4; ++j) hb[j] = f2bf(hy[j]);
          if (Lb == 0){
            *(volatile u16x4*)&hA[(size_t)tb * BH + bb * HID + e] = hb;
          } else {
            *(f32x4*)&out[((size_t)tb * BATCH + bb) * HID + e] = hy;
            *(volatile u16x4*)&hB[(size_t)tb * BH + bb * HID + e] = hb;
          }
        }
        drain_sync();
        bar_add(bar2, wg);
        bar_spin(bar2, tgt);
      } else {
        bar_add(bar2, wg);
        bar_spin(bar2, tgt);
      }
    }
  }
}

// ---- launch -----------------------------------------------------------------

extern "C" void kernel_launch(void* const* d_in, const int* in_sizes, int n_in,
                              void* d_out, int out_size, void* d_ws, size_t ws_size,
                              hipStream_t stream)
{
  (void)in_sizes; (void)n_in; (void)out_size; (void)ws_size;
  const int*   tokens = (const int*)d_in[0];
  const float* emb    = (const float*)d_in[1];
  const float* Wih0   = (const float*)d_in[2];
  const float* bih0   = (const float*)d_in[3];
  const float* Whh0   = (const float*)d_in[4];
  const float* bhh0   = (const float*)d_in[5];
  const float* Wih1   = (const float*)d_in[6];
  const float* bih1   = (const float*)d_in[7];
  const float* Whh1   = (const float*)d_in[8];
  const float* bhh1   = (const float*)d_in[9];
  float* out = (float*)d_out;

  char* ws = (char*)d_ws;
  u16*   Wt0    = (u16*)(ws);                     // 16,908,288
  u16*   Wt1    = (u16*)(ws + 16908288);          // 16,908,288
  u16*   x      = (u16*)(ws + 33816576);          // 33,554,432
  u16*   hA     = (u16*)(ws + 67371008);          // 33,554,432 (full history h1)
  u16*   hB     = (u16*)(ws + 100925440);         // 33,554,432 (full history h2)
  float* bias0  = (float*)(ws + 134479872);       // 16,512
  float* bias1  = (float*)(ws + 134496384);       // 16,512
  float* gates0 = (float*)(ws + 134512896);       // 1,056,768
  float* gates1 = (float*)(ws + 135569664);       // 1,056,768
  u16*   zerob  = (u16*)(ws + 136626432);         // 131,072 (zeroed)
  unsigned* bar1 = (unsigned*)(ws + 136757504);   // 1,024
  unsigned* bar2 = (unsigned*)(ws + 136758528);   // 1,024

  repackW<<<dim3(64,129), dim3(32,32), 0, stream>>>(Wih0, Whh0, Wt0);
  repackW<<<dim3(64,129), dim3(32,32), 0, stream>>>(Wih1, Whh1, Wt1);
  gatherX<<<16384, 256, 0, stream>>>(tokens, emb, x, out + 16777216);
  biasK<<<17, 256, 0, stream>>>(bih0, bhh0, bih1, bhh1, bias0, bias1);
  zeroK<<<32, 256, 0, stream>>>((int4v*)zerob);
  hipMemsetAsync(bar1, 0, 2048, stream);

  persist<<<NWG, 512, 0, stream>>>(Wt0, Wt1, bias0, bias1, x, hA, hB, zerob,
                                   gates0, gates1, out, bar1, bar2);
}